// Round 6
// baseline (267.397 us; speedup 1.0000x reference)
//
#include <hip/hip_runtime.h>
#include <math.h>

// Problem constants
#define N_NODES 69
#define MP      80        // padded M (adjacency rows), 5 tiles of 16
#define KP      96        // padded K (adjacency cols), 3 tiles of 32
#define BT_TOTAL 32768
#define F_IN    8
#define H1      32
#define H2      16

#define TBT     8         // bt-instances per block
#define BLOCK   256       // 4 waves

#define ZPITCH3 104       // Zt: [128 rows=(bt,h2)][104 cols=n]; 208B row stride -> 2-way-free b128
#define HBPITCH 40        // Hb: [16 rows=n][40 cols=h]

typedef __attribute__((ext_vector_type(8))) short bf16x8;
typedef __attribute__((ext_vector_type(4))) float f32x4;
typedef __attribute__((ext_vector_type(2), aligned(8)))  unsigned u32x2;
typedef __attribute__((ext_vector_type(4), aligned(16))) unsigned u32x4;

// may_alias variants for all cross-typed LDS accesses (keep store->load deps)
typedef bf16x8 __attribute__((may_alias)) bf16x8_a;
typedef u32x2  __attribute__((may_alias)) u32x2_a;
typedef u32x4  __attribute__((may_alias)) u32x4_a;

__device__ __forceinline__ unsigned short f2bf(float f) {
    unsigned u = __float_as_uint(f);
    return (unsigned short)((u + 0x7FFFu + ((u >> 16) & 1u)) >> 16);
}
__device__ __forceinline__ float bf2f(unsigned short h) {
    return __uint_as_float(((unsigned)h) << 16);
}

// ---------------------------------------------------------------------------
// Setup: ONLY the adjn hi/lo planes [MP][KP] (round-0 verbatim code path).
// W1/W2 fragments are now built in-register inside gcn_kernel, so the
// workspace footprint (30,720 B) stays below round-0's proven 33,792 B.
// ---------------------------------------------------------------------------
__global__ void setup_kernel(const float* __restrict__ adj,
                             unsigned short* __restrict__ adjh,
                             unsigned short* __restrict__ adjl)
{
    __shared__ float dinv[N_NODES];
    const int tid = threadIdx.x;
    if (tid < N_NODES) {
        float s = 1.0f;
        for (int j = 0; j < N_NODES; ++j) s += adj[tid * N_NODES + j];
        dinv[tid] = rsqrtf(s);
    }
    __syncthreads();
    for (int idx = tid; idx < MP * KP; idx += BLOCK) {
        const int n = idx / KP, m = idx % KP;
        float v = 0.0f;
        if (n < N_NODES && m < N_NODES) {
            float a = adj[n * N_NODES + m] + (n == m ? 1.0f : 0.0f);
            v = a * dinv[n] * dinv[m];
        }
        unsigned short h = f2bf(v);
        adjh[idx] = h;
        adjl[idx] = f2bf(v - bf2f(h));
    }
}

// ---------------------------------------------------------------------------
// Main kernel.
//   P1 (round-5 verified): Y1^T = X^T @ adjn, acc[nt][reg] =
//       Y1[n=nt*16+l16][bt=wv*2+(quad>>1)][f=(quad&1)*4+reg]  (harness-proven)
//   P2 (zero-shuffle): af={d0,d1,d0,d1} is a valid A-frag whose per-quad k-rows
//       carry (bt,f) = (quad>>1, quad*4+(j&3) mod 8); sparse W1 B-variants
//       annihilate the unwanted rows:
//         v=0 (bt even): B rows {0-3}->W1[0-3], {8-11}->W1[4-7], else 0
//         v=1 (bt odd) : B rows {16-19}->W1[0-3], {24-27}->W1[4-7], else 0
//       H -> per-wave Hb transpose (round-0/5-verified) -> Z = H@W2 ->
//       Zt[(bt*16+h2)][n] as packed u32x2 (C rows = consecutive n).
//   P3: out = sigmoid(adjn @ Z); B-frags are single b128 reads from Zt
//       (bz[j] = Z[node=kt*32+quad*8+j][bt=c][h2=l16]).
//   Zt/Hb are wave-private throughout; the one barrier is defensive.
// ---------------------------------------------------------------------------
__global__ __launch_bounds__(BLOCK, 5) void gcn_kernel(
    const float* __restrict__ x,              // [69][BT][8]
    const unsigned short* __restrict__ adjh,  // [80][96]
    const unsigned short* __restrict__ adjl,  // [80][96]
    const float* __restrict__ W1g,            // [8][32]
    const float* __restrict__ W2g,            // [32][16]
    float* __restrict__ out)                  // [BT][69][16]
{
    __shared__ unsigned short Zt[128 * ZPITCH3];       // 26624 B
    __shared__ unsigned short Hb_s[4][16 * HBPITCH];   // 5120 B
    // total 31744 B -> 5 blocks/CU

    const int tid  = threadIdx.x;
    const int lane = tid & 63;
    const int wv   = tid >> 6;
    const int quad = lane >> 4;
    const int l16  = lane & 15;
    const int bt0  = blockIdx.x * TBT;

    // zero Zt pad cols 80..95 for this wave's 32 rows (read by P3 kt=2)
    {
        const int row = wv * 32 + (lane >> 1);
        const int col = 80 + (lane & 1) * 8;
        *(u32x4_a*)&Zt[row * ZPITCH3 + col] = (u32x4){0u, 0u, 0u, 0u};
    }

    // ---- phase 1 (round-5 verified): Y1^T = X^T @ adjn ----------------
    const int btg = bt0 + wv * 2 + (l16 >> 3);
    const int fl  = l16 & 7;

    f32x4 acc[5] = {};
#pragma unroll
    for (int kt = 0; kt < 3; ++kt) {
        union AF { unsigned u[4]; bf16x8 v; } ah, al;
#pragma unroll
        for (int p = 0; p < 4; ++p) {
            const int m0 = kt * 32 + quad * 8 + 2 * p;
            const int m1 = m0 + 1;
            float x0 = 0.0f, x1 = 0.0f;
            if (kt < 2) {                       // m <= 63: always valid
                x0 = x[(size_t)m0 * 262144 + btg * 8 + fl];
                x1 = x[(size_t)m1 * 262144 + btg * 8 + fl];
            } else {                            // padded rows m >= 69 -> 0
                if (m0 < N_NODES) x0 = x[(size_t)m0 * 262144 + btg * 8 + fl];
                if (m1 < N_NODES) x1 = x[(size_t)m1 * 262144 + btg * 8 + fl];
            }
            const unsigned short h0 = f2bf(x0), h1 = f2bf(x1);
            ah.u[p] = (unsigned)h0 | ((unsigned)h1 << 16);
            const unsigned short g0 = f2bf(x0 - bf2f(h0));
            const unsigned short g1 = f2bf(x1 - bf2f(h1));
            al.u[p] = (unsigned)g0 | ((unsigned)g1 << 16);
        }
#pragma unroll
        for (int nt = 0; nt < 5; ++nt) {
            const int boff = (nt * 16 + l16) * KP + kt * 32 + quad * 8;
            const bf16x8 bh = *(const bf16x8_a*)(adjh + boff);
            const bf16x8 bl = *(const bf16x8_a*)(adjl + boff);
            acc[nt] = __builtin_amdgcn_mfma_f32_16x16x32_bf16(ah.v, bh, acc[nt], 0, 0, 0);
            acc[nt] = __builtin_amdgcn_mfma_f32_16x16x32_bf16(ah.v, bl, acc[nt], 0, 0, 0);
            acc[nt] = __builtin_amdgcn_mfma_f32_16x16x32_bf16(al.v, bh, acc[nt], 0, 0, 0);
        }
    }

    // ---- W fragments built in-register from raw global weights --------
    // W1 sparse variants: v=0 nonzero iff quad<2 && j<4, f = quad*4+j;
    //                     v=1 nonzero iff quad>=2 && j<4, f = (quad-2)*4+j.
    bf16x8 w1f[2][2] = {};   // [v][ht]; elements 4..7 stay zero
    {
        const int fb0 = quad * 4;
        const int fb1 = (quad - 2) * 4;
#pragma unroll
        for (int ht = 0; ht < 2; ++ht) {
#pragma unroll
            for (int j = 0; j < 4; ++j) {
                const float a0 = (quad < 2)  ? W1g[(fb0 + j) * H1 + ht * 16 + l16] : 0.0f;
                const float a1 = (quad >= 2) ? W1g[(fb1 + j) * H1 + ht * 16 + l16] : 0.0f;
                w1f[0][ht][j] = (short)f2bf(a0);
                w1f[1][ht][j] = (short)f2bf(a1);
            }
        }
    }
    // W2 full B-frag: B[k=quad*8+j][l16] = W2[k][l16]
    bf16x8 w2f;
#pragma unroll
    for (int j = 0; j < 8; ++j)
        w2f[j] = (short)f2bf(W2g[(quad * 8 + j) * H2 + l16]);

    // ---- phase 2: H = relu(Y1@W1); Z = H@W2 -> Zt ---------------------
    unsigned short* Hb = Hb_s[wv];

    auto do_bt = [&](const f32x4& h0, const f32x4& h1, int btl, int nt) {
        // H C-layout: lane l16 = h-col, rows n = quad*4+reg -> Hb[n][h]
#pragma unroll
        for (int reg = 0; reg < 4; ++reg) {
            const int row = quad * 4 + reg;
            Hb[row * HBPITCH + l16]      = f2bf(fmaxf(h0[reg], 0.f));
            Hb[row * HBPITCH + 16 + l16] = f2bf(fmaxf(h1[reg], 0.f));
        }
        // same-wave LDS RAW/WAR: DS ops are wave-ordered (round-0-proven)
        const bf16x8 a2 = *(const bf16x8_a*)&Hb[l16 * HBPITCH + quad * 8];
        f32x4 zk = {0.f, 0.f, 0.f, 0.f};
        zk = __builtin_amdgcn_mfma_f32_16x16x32_bf16(a2, w2f, zk, 0, 0, 0);
        // Z C-layout: lane l16 = h2, rows n = quad*4+reg (consecutive)
        //   -> Zt[(btl*16 + h2)][n]: 4 contiguous bf16 = one b64 write
        const unsigned z0 = (unsigned)f2bf(zk[0]) | ((unsigned)f2bf(zk[1]) << 16);
        const unsigned z1 = (unsigned)f2bf(zk[2]) | ((unsigned)f2bf(zk[3]) << 16);
        *(u32x2_a*)&Zt[(btl * 16 + l16) * ZPITCH3 + nt * 16 + quad * 4] = (u32x2){z0, z1};
    };

#pragma unroll
    for (int nt = 0; nt < 5; ++nt) {
        // af = {d0,d1,d0,d1}: per-quad k-rows carry this lane's acc regs;
        // sparse W1 variants zero the unwanted (bt,f) rows -> no shuffles.
        const unsigned d0 = (unsigned)f2bf(acc[nt][0]) | ((unsigned)f2bf(acc[nt][1]) << 16);
        const unsigned d1 = (unsigned)f2bf(acc[nt][2]) | ((unsigned)f2bf(acc[nt][3]) << 16);
        union AF { unsigned u[4]; bf16x8 v; } af;
        af.u[0] = d0; af.u[1] = d1; af.u[2] = d0; af.u[3] = d1;

        const f32x4 zz = {0.f, 0.f, 0.f, 0.f};
        f32x4 hL0 = __builtin_amdgcn_mfma_f32_16x16x32_bf16(af.v, w1f[0][0], zz, 0, 0, 0);
        f32x4 hL1 = __builtin_amdgcn_mfma_f32_16x16x32_bf16(af.v, w1f[0][1], zz, 0, 0, 0);
        f32x4 hH0 = __builtin_amdgcn_mfma_f32_16x16x32_bf16(af.v, w1f[1][0], zz, 0, 0, 0);
        f32x4 hH1 = __builtin_amdgcn_mfma_f32_16x16x32_bf16(af.v, w1f[1][1], zz, 0, 0, 0);

        do_bt(hL0, hL1, wv * 2 + 0, nt);
        do_bt(hH0, hH1, wv * 2 + 1, nt);
    }

    // Defensive fence (Zt traffic is wave-private; this only pins ordering).
    __syncthreads();

    // ---- phase 3: out = sigmoid(adjn @ Z) -----------------------------
    bf16x8 bz[2][3];
#pragma unroll
    for (int c = 0; c < 2; ++c)
#pragma unroll
        for (int kt = 0; kt < 3; ++kt)
            bz[c][kt] = *(const bf16x8_a*)
                &Zt[((wv * 2 + c) * 16 + l16) * ZPITCH3 + kt * 32 + quad * 8];

#pragma unroll
    for (int mt = 0; mt < 5; ++mt) {
        bf16x8 am[3];
#pragma unroll
        for (int kt = 0; kt < 3; ++kt)
            am[kt] = *(const bf16x8_a*)&adjh[(mt * 16 + l16) * KP + kt * 32 + quad * 8];
#pragma unroll
        for (int c = 0; c < 2; ++c) {
            f32x4 a3 = {0.f, 0.f, 0.f, 0.f};
#pragma unroll
            for (int kt = 0; kt < 3; ++kt)
                a3 = __builtin_amdgcn_mfma_f32_16x16x32_bf16(am[kt], bz[c][kt], a3, 0, 0, 0);
            const int ct3 = wv * 2 + c;
            float* outc = out + ((size_t)(bt0 + ct3) * N_NODES) * H2 + l16;
#pragma unroll
            for (int reg = 0; reg < 4; ++reg) {
                const int n = mt * 16 + quad * 4 + reg;
                if (n < N_NODES) {
                    const float v = 1.0f / (1.0f + __expf(-a3[reg]));
                    outc[n * H2] = v;
                }
            }
        }
    }
}

// ---------------------------------------------------------------------------
extern "C" void kernel_launch(void* const* d_in, const int* in_sizes, int n_in,
                              void* d_out, int out_size, void* d_ws, size_t ws_size,
                              hipStream_t stream) {
    const float* x   = (const float*)d_in[0];
    const float* adj = (const float*)d_in[1];
    const float* W1  = (const float*)d_in[2];
    const float* W2  = (const float*)d_in[3];
    float* out = (float*)d_out;

    unsigned short* adjh = (unsigned short*)d_ws;       // 80*96
    unsigned short* adjl = adjh + MP * KP;              // 80*96  (total 30,720 B)

    setup_kernel<<<1, BLOCK, 0, stream>>>(adj, adjh, adjl);
    gcn_kernel<<<BT_TOTAL / TBT, BLOCK, 0, stream>>>(x, adjh, adjl, W1, W2, out);
}

// Round 7
// 259.239 us; speedup vs baseline: 1.0315x; 1.0315x over previous
//
#include <hip/hip_runtime.h>
#include <math.h>

// Problem constants
#define N_NODES 69
#define MP      80        // padded M (adjacency rows), 5 tiles of 16
#define KP      96        // padded K (adjacency cols), 3 tiles of 32
#define BT_TOTAL 32768
#define F_IN    8
#define H1      32
#define H2      16

#define TBT     8         // bt-instances per block
#define BLOCK   256       // 4 waves

#define ZPITCH3 104       // Zt: [128 rows=(bt,h2)][104 cols=n]; 208B row stride -> 2-way-free b128
#define HBPITCH 40        // Hb: [16 rows=n][40 cols=h]

typedef __attribute__((ext_vector_type(8))) short bf16x8;
typedef __attribute__((ext_vector_type(4))) float f32x4;
typedef __attribute__((ext_vector_type(2), aligned(8)))  unsigned u32x2;
typedef __attribute__((ext_vector_type(4), aligned(16))) unsigned u32x4;

// may_alias variants for all cross-typed LDS accesses (keep store->load deps)
typedef bf16x8 __attribute__((may_alias)) bf16x8_a;
typedef u32x2  __attribute__((may_alias)) u32x2_a;
typedef u32x4  __attribute__((may_alias)) u32x4_a;

__device__ __forceinline__ unsigned short f2bf(float f) {
    unsigned u = __float_as_uint(f);
    return (unsigned short)((u + 0x7FFFu + ((u >> 16) & 1u)) >> 16);
}
__device__ __forceinline__ float bf2f(unsigned short h) {
    return __uint_as_float(((unsigned)h) << 16);
}

// ---------------------------------------------------------------------------
// Setup (round-6 verbatim): adjn hi/lo planes [MP][KP] only. 30,720 B ws.
// ---------------------------------------------------------------------------
__global__ void setup_kernel(const float* __restrict__ adj,
                             unsigned short* __restrict__ adjh,
                             unsigned short* __restrict__ adjl)
{
    __shared__ float dinv[N_NODES];
    const int tid = threadIdx.x;
    if (tid < N_NODES) {
        float s = 1.0f;
        for (int j = 0; j < N_NODES; ++j) s += adj[tid * N_NODES + j];
        dinv[tid] = rsqrtf(s);
    }
    __syncthreads();
    for (int idx = tid; idx < MP * KP; idx += BLOCK) {
        const int n = idx / KP, m = idx % KP;
        float v = 0.0f;
        if (n < N_NODES && m < N_NODES) {
            float a = adj[n * N_NODES + m] + (n == m ? 1.0f : 0.0f);
            v = a * dinv[n] * dinv[m];
        }
        unsigned short h = f2bf(v);
        adjh[idx] = h;
        adjl[idx] = f2bf(v - bf2f(h));
    }
}

// ---------------------------------------------------------------------------
// Main kernel (round-6 structure; register-side MLP changes only):
//   * ahf[15]: ALL adjh fragments persistent in VGPRs -- P1 B-frags and P3
//     A-frags share the same per-lane addresses, so P3 needs no global loads.
//   * xv[3][8]: all 24 X loads issued upfront (full HBM MLP).
//   * Hb double-buffered per wave: the two do_bt LDS round-trips per nt
//     overlap instead of WAR-serializing on one buffer.
// ---------------------------------------------------------------------------
__global__ __launch_bounds__(BLOCK, 4) void gcn_kernel(
    const float* __restrict__ x,              // [69][BT][8]
    const unsigned short* __restrict__ adjh,  // [80][96]
    const unsigned short* __restrict__ adjl,  // [80][96]
    const float* __restrict__ W1g,            // [8][32]
    const float* __restrict__ W2g,            // [32][16]
    float* __restrict__ out)                  // [BT][69][16]
{
    __shared__ unsigned short Zt[128 * ZPITCH3];          // 26624 B
    __shared__ unsigned short Hb_s[4][2][16 * HBPITCH];   // 10240 B
    // total 36864 B -> 4 blocks/CU

    const int tid  = threadIdx.x;
    const int lane = tid & 63;
    const int wv   = tid >> 6;
    const int quad = lane >> 4;
    const int l16  = lane & 15;
    const int bt0  = blockIdx.x * TBT;

    // zero Zt pad cols 80..95 for this wave's 32 rows (read by P3 kt=2)
    {
        const int row = wv * 32 + (lane >> 1);
        const int col = 80 + (lane & 1) * 8;
        *(u32x4_a*)&Zt[row * ZPITCH3 + col] = (u32x4){0u, 0u, 0u, 0u};
    }

    // ---- persistent adjacency-hi fragments (60 VGPR, loaded once) -----
    // ahf[t= nt*3+kt] = adjh row (nt*16+l16), k-slot (kt,quad): used as
    // P1 B-frags (symmetry) AND P3 A-frags (identical addresses).
    bf16x8 ahf[15];
#pragma unroll
    for (int t = 0; t < 15; ++t) {
        const int nt = t / 3, kt = t % 3;
        ahf[t] = *(const bf16x8_a*)&adjh[(nt * 16 + l16) * KP + kt * 32 + quad * 8];
    }

    // ---- phase 1: Y1^T = X^T @ adjn -----------------------------------
    // (round-5/6 verified: acc[nt][reg] =
    //  Y1[n=nt*16+l16][bt=wv*2+(quad>>1)][f=(quad&1)*4+reg])
    const int btg = bt0 + wv * 2 + (l16 >> 3);
    const int fl  = l16 & 7;

    // all 24 X loads upfront: maximum memory-level parallelism
    float xv[3][8];
#pragma unroll
    for (int kt = 0; kt < 3; ++kt) {
#pragma unroll
        for (int p = 0; p < 4; ++p) {
            const int m0 = kt * 32 + quad * 8 + 2 * p;
            const int m1 = m0 + 1;
            if (kt < 2) {                       // m <= 63: always valid
                xv[kt][2 * p]     = x[(size_t)m0 * 262144 + btg * 8 + fl];
                xv[kt][2 * p + 1] = x[(size_t)m1 * 262144 + btg * 8 + fl];
            } else {                            // padded rows m >= 69 -> 0
                xv[kt][2 * p]     = (m0 < N_NODES) ? x[(size_t)m0 * 262144 + btg * 8 + fl] : 0.0f;
                xv[kt][2 * p + 1] = (m1 < N_NODES) ? x[(size_t)m1 * 262144 + btg * 8 + fl] : 0.0f;
            }
        }
    }

    f32x4 acc[5] = {};
#pragma unroll
    for (int kt = 0; kt < 3; ++kt) {
        union AF { unsigned u[4]; bf16x8 v; } ah, al;
#pragma unroll
        for (int p = 0; p < 4; ++p) {
            const float x0 = xv[kt][2 * p], x1 = xv[kt][2 * p + 1];
            const unsigned short h0 = f2bf(x0), h1 = f2bf(x1);
            ah.u[p] = (unsigned)h0 | ((unsigned)h1 << 16);
            const unsigned short g0 = f2bf(x0 - bf2f(h0));
            const unsigned short g1 = f2bf(x1 - bf2f(h1));
            al.u[p] = (unsigned)g0 | ((unsigned)g1 << 16);
        }
        // adjl fragments for this kt (20 VGPR transient, overlappable loads)
        bf16x8 alf[5];
#pragma unroll
        for (int nt = 0; nt < 5; ++nt)
            alf[nt] = *(const bf16x8_a*)&adjl[(nt * 16 + l16) * KP + kt * 32 + quad * 8];
#pragma unroll
        for (int nt = 0; nt < 5; ++nt) {
            acc[nt] = __builtin_amdgcn_mfma_f32_16x16x32_bf16(ah.v, ahf[nt * 3 + kt], acc[nt], 0, 0, 0);
            acc[nt] = __builtin_amdgcn_mfma_f32_16x16x32_bf16(ah.v, alf[nt], acc[nt], 0, 0, 0);
            acc[nt] = __builtin_amdgcn_mfma_f32_16x16x32_bf16(al.v, ahf[nt * 3 + kt], acc[nt], 0, 0, 0);
        }
    }

    // ---- W fragments built in-register (round-6 verified) -------------
    bf16x8 w1f[2][2] = {};   // [v][ht]; elements 4..7 stay zero
    {
        const int fb0 = quad * 4;
        const int fb1 = (quad - 2) * 4;
#pragma unroll
        for (int ht = 0; ht < 2; ++ht) {
#pragma unroll
            for (int j = 0; j < 4; ++j) {
                const float a0 = (quad < 2)  ? W1g[(fb0 + j) * H1 + ht * 16 + l16] : 0.0f;
                const float a1 = (quad >= 2) ? W1g[(fb1 + j) * H1 + ht * 16 + l16] : 0.0f;
                w1f[0][ht][j] = (short)f2bf(a0);
                w1f[1][ht][j] = (short)f2bf(a1);
            }
        }
    }
    bf16x8 w2f;
#pragma unroll
    for (int j = 0; j < 8; ++j)
        w2f[j] = (short)f2bf(W2g[(quad * 8 + j) * H2 + l16]);

    // ---- phase 2: H = relu(Y1@W1); Z = H@W2 -> Zt ---------------------
    auto do_bt = [&](const f32x4& h0, const f32x4& h1, int btl, int nt,
                     unsigned short* Hb) {
        // H C-layout: lane l16 = h-col, rows n = quad*4+reg -> Hb[n][h]
#pragma unroll
        for (int reg = 0; reg < 4; ++reg) {
            const int row = quad * 4 + reg;
            Hb[row * HBPITCH + l16]      = f2bf(fmaxf(h0[reg], 0.f));
            Hb[row * HBPITCH + 16 + l16] = f2bf(fmaxf(h1[reg], 0.f));
        }
        // same-wave LDS RAW: DS ops are wave-ordered (round-0/6-proven)
        const bf16x8 a2 = *(const bf16x8_a*)&Hb[l16 * HBPITCH + quad * 8];
        f32x4 zk = {0.f, 0.f, 0.f, 0.f};
        zk = __builtin_amdgcn_mfma_f32_16x16x32_bf16(a2, w2f, zk, 0, 0, 0);
        // Z C-layout: lane l16 = h2, rows n = quad*4+reg (consecutive)
        //   -> Zt[(btl*16 + h2)][n]: 4 contiguous bf16 = one b64 write
        const unsigned z0 = (unsigned)f2bf(zk[0]) | ((unsigned)f2bf(zk[1]) << 16);
        const unsigned z1 = (unsigned)f2bf(zk[2]) | ((unsigned)f2bf(zk[3]) << 16);
        *(u32x2_a*)&Zt[(btl * 16 + l16) * ZPITCH3 + nt * 16 + quad * 4] = (u32x2){z0, z1};
    };

#pragma unroll
    for (int nt = 0; nt < 5; ++nt) {
        // af = {d0,d1,d0,d1}: per-quad k-rows carry this lane's acc regs;
        // sparse W1 variants zero the unwanted (bt,f) rows -> no shuffles.
        const unsigned d0 = (unsigned)f2bf(acc[nt][0]) | ((unsigned)f2bf(acc[nt][1]) << 16);
        const unsigned d1 = (unsigned)f2bf(acc[nt][2]) | ((unsigned)f2bf(acc[nt][3]) << 16);
        union AF { unsigned u[4]; bf16x8 v; } af;
        af.u[0] = d0; af.u[1] = d1; af.u[2] = d0; af.u[3] = d1;

        const f32x4 zz = {0.f, 0.f, 0.f, 0.f};
        f32x4 hL0 = __builtin_amdgcn_mfma_f32_16x16x32_bf16(af.v, w1f[0][0], zz, 0, 0, 0);
        f32x4 hL1 = __builtin_amdgcn_mfma_f32_16x16x32_bf16(af.v, w1f[0][1], zz, 0, 0, 0);
        f32x4 hH0 = __builtin_amdgcn_mfma_f32_16x16x32_bf16(af.v, w1f[1][0], zz, 0, 0, 0);
        f32x4 hH1 = __builtin_amdgcn_mfma_f32_16x16x32_bf16(af.v, w1f[1][1], zz, 0, 0, 0);

        // independent Hb buffers: the two LDS round-trip chains overlap
        do_bt(hL0, hL1, wv * 2 + 0, nt, &Hb_s[wv][0][0]);
        do_bt(hH0, hH1, wv * 2 + 1, nt, &Hb_s[wv][1][0]);
    }

    // Defensive fence (Zt traffic is wave-private; this only pins ordering).
    __syncthreads();

    // ---- phase 3: out = sigmoid(adjn @ Z) -----------------------------
    bf16x8 bz[2][3];
#pragma unroll
    for (int c = 0; c < 2; ++c)
#pragma unroll
        for (int kt = 0; kt < 3; ++kt)
            bz[c][kt] = *(const bf16x8_a*)
                &Zt[((wv * 2 + c) * 16 + l16) * ZPITCH3 + kt * 32 + quad * 8];

#pragma unroll
    for (int mt = 0; mt < 5; ++mt) {
#pragma unroll
        for (int c = 0; c < 2; ++c) {
            f32x4 a3 = {0.f, 0.f, 0.f, 0.f};
#pragma unroll
            for (int kt = 0; kt < 3; ++kt)
                a3 = __builtin_amdgcn_mfma_f32_16x16x32_bf16(ahf[mt * 3 + kt], bz[c][kt], a3, 0, 0, 0);
            const int ct3 = wv * 2 + c;
            float* outc = out + ((size_t)(bt0 + ct3) * N_NODES) * H2 + l16;
#pragma unroll
            for (int reg = 0; reg < 4; ++reg) {
                const int n = mt * 16 + quad * 4 + reg;
                if (n < N_NODES) {
                    const float v = 1.0f / (1.0f + __expf(-a3[reg]));
                    outc[n * H2] = v;
                }
            }
        }
    }
}

// ---------------------------------------------------------------------------
extern "C" void kernel_launch(void* const* d_in, const int* in_sizes, int n_in,
                              void* d_out, int out_size, void* d_ws, size_t ws_size,
                              hipStream_t stream) {
    const float* x   = (const float*)d_in[0];
    const float* adj = (const float*)d_in[1];
    const float* W1  = (const float*)d_in[2];
    const float* W2  = (const float*)d_in[3];
    float* out = (float*)d_out;

    unsigned short* adjh = (unsigned short*)d_ws;       // 80*96
    unsigned short* adjl = adjh + MP * KP;              // 80*96  (total 30,720 B)

    setup_kernel<<<1, BLOCK, 0, stream>>>(adj, adjh, adjl);
    gcn_kernel<<<BT_TOTAL / TBT, BLOCK, 0, stream>>>(x, adjh, adjl, W1, W2, out);
}